// Round 5
// baseline (164.948 us; speedup 1.0000x reference)
//
#include <hip/hip_runtime.h>

#define H2    1024
#define LSRC  1024
#define BATCH 64
#define NCH   32            // l-chunks
#define CH    32            // LSRC / NCH, rows per block

__device__ __forceinline__ float fast_tanh(float x) {
  // tanh(x) = 1 - 2/(exp(2x)+1); saturates correctly (exp->inf => 1, exp->0 => -1)
  float e2 = __expf(2.0f * x);
  return 1.0f - 2.0f * __builtin_amdgcn_rcpf(e2 + 1.0f);
}

// dec[b][h] = sum_k s[b][k] * W[h][k] + bias[h]
__global__ __launch_bounds__(256) void dec_kernel(
    const float* __restrict__ s, const float* __restrict__ W,
    const float* __restrict__ bias, float* __restrict__ dec) {
  const int KT = 128;
  __shared__ float s_lds[BATCH][KT + 1];
  __shared__ float w_lds[16][KT];
  const int t  = threadIdx.x;
  const int h0 = blockIdx.x * 16;
  const int bi = t & 63;
  const int hg = t >> 6;  // 0..3
  float acc[4] = {0.f, 0.f, 0.f, 0.f};
  for (int k0 = 0; k0 < H2; k0 += KT) {
    __syncthreads();
    for (int idx = t; idx < BATCH * KT; idx += 256) {
      int r = idx >> 7, c = idx & (KT - 1);
      s_lds[r][c] = s[r * H2 + k0 + c];
    }
    for (int idx = t; idx < 16 * KT; idx += 256) {
      int r = idx >> 7, c = idx & (KT - 1);
      w_lds[r][c] = W[(h0 + r) * H2 + k0 + c];
    }
    __syncthreads();
    for (int k = 0; k < KT; ++k) {
      float sv = s_lds[bi][k];
#pragma unroll
      for (int j = 0; j < 4; ++j) acc[j] += sv * w_lds[hg + 4 * j][k];
    }
  }
#pragma unroll
  for (int j = 0; j < 4; ++j) {
    int h = h0 + hg + 4 * j;
    dec[bi * H2 + h] = acc[j] + bias[h];
  }
}

// Fused e + shift-free softmax weight + weighted-eo partial, per (l-chunk, b).
// Shift-free safe: |e| <= ||v||_1 ~= 16.4 (tanh in [-1,1]); 80-clamp guard.
// Phase A is column-parallel: wave w owns h-slice [256w,256w+256), one float4
// per lane; 32 rows -> 32 INDEPENDENT coalesced loads, no cross-lane ops in
// the stream loop. Row sums via one 32-shfl butterfly at the end.
__global__ __launch_bounds__(256, 4) void fused_kernel(
    const float* __restrict__ ef, const float* __restrict__ eo,
    const float* __restrict__ dec, const float* __restrict__ v,
    const float* __restrict__ mask, float* __restrict__ part,
    float* __restrict__ sums) {
  __shared__ float apart[4][32];
  __shared__ float a_lds[CH];
  const int t    = threadIdx.x;
  const int lane = t & 63;
  const int wave = t >> 6;
  const int lc   = blockIdx.x;
  const int b    = blockIdx.y;
  const int l0   = lc * CH;

  // loop-invariant slice of dec/v for this (wave, lane): ONE float4 each
  const int hq = wave * 64 + lane;  // float4 index in [0,256)
  float4 dj = ((const float4*)(dec + (size_t)b * H2))[hq];
  float4 vj = ((const float4*)v)[hq];

  // ---- phase A: per-lane partials for 32 rows (pure stream, max MLP) ----
  const float4* efb = (const float4*)(ef) + ((size_t)b * LSRC + l0) * 256 + hq;
  float a[CH];
#pragma unroll
  for (int r = 0; r < CH; ++r) {
    float4 x = efb[(size_t)r * 256];   // 1KB coalesced per (wave,r)
    a[r] = fast_tanh(x.x + dj.x) * vj.x + fast_tanh(x.y + dj.y) * vj.y +
           fast_tanh(x.z + dj.z) * vj.z + fast_tanh(x.w + dj.w) * vj.w;
  }
  // halving butterfly: 32 rows x 64 lanes -> row l>>1 total in lane pairs
#pragma unroll
  for (int m = 32; m >= 2; m >>= 1) {
    const int nh = m >> 1;
    const bool hi = (lane & m) != 0;
#pragma unroll
    for (int r = 0; r < nh; ++r) {
      float send = hi ? a[r] : a[r + nh];
      float recv = __shfl_xor(send, m);
      a[r] = (hi ? a[r + nh] : a[r]) + recv;
    }
  }
  a[0] += __shfl_xor(a[0], 1);
  if (!(lane & 1)) apart[wave][lane >> 1] = a[0];
  __syncthreads();

  // wave 0: combine 4 wave-slices, exp*mask, chunk sum
  float wv = 0.f;
  if (t < 32) {
    float es = apart[0][t] + apart[1][t] + apart[2][t] + apart[3][t];
    wv = __expf(fminf(es, 80.f)) * mask[b * LSRC + l0 + t];
    a_lds[t] = wv;
  }
#pragma unroll
  for (int off = 32; off >= 1; off >>= 1) wv += __shfl_xor(wv, off);
  if (t == 0) sums[b * NCH + lc] = wv;
  __syncthreads();

  // ---- phase B: part[lc][b][h] = sum_l w[l] * eo[b][l][h] ----
  const float4* eob = (const float4*)(eo) + ((size_t)b * LSRC + l0) * 256;
  float4 acc = {0.f, 0.f, 0.f, 0.f};
#pragma unroll
  for (int l = 0; l < CH; ++l) {
    float  av = a_lds[l];                   // LDS broadcast
    float4 x  = eob[(size_t)l * 256 + t];   // coalesced 1KB/wave, independent
    acc.x += av * x.x; acc.y += av * x.y; acc.z += av * x.z; acc.w += av * x.w;
  }
  ((float4*)(part) + (size_t)(lc * BATCH + b) * 256)[t] = acc;
}

// out[b][h] = (sum_lc part[lc][b][h]) / (sum_lc sums[b][lc])
__global__ __launch_bounds__(256) void reduce_kernel(
    const float* __restrict__ part, const float* __restrict__ sums,
    float* __restrict__ out) {
  const int b = blockIdx.x, t = threadIdx.x;
  float Z = 0.f;
#pragma unroll
  for (int lc = 0; lc < NCH; ++lc) Z += sums[b * NCH + lc];
  float inv = 1.0f / Z;
  float4 s = {0.f, 0.f, 0.f, 0.f};
#pragma unroll
  for (int lc = 0; lc < NCH; ++lc) {
    float4 x = ((const float4*)(part) + (size_t)(lc * BATCH + b) * 256)[t];
    s.x += x.x; s.y += x.y; s.z += x.z; s.w += x.w;
  }
  float4 o = {s.x * inv, s.y * inv, s.z * inv, s.w * inv};
  ((float4*)(out) + (size_t)b * 256)[t] = o;
}

extern "C" void kernel_launch(void* const* d_in, const int* in_sizes, int n_in,
                              void* d_out, int out_size, void* d_ws, size_t ws_size,
                              hipStream_t stream) {
  const float* s_t_hat  = (const float*)d_in[0];
  const float* enc_out  = (const float*)d_in[1];
  const float* enc_feat = (const float*)d_in[2];
  const float* mask     = (const float*)d_in[3];
  const float* W        = (const float*)d_in[4];
  const float* bias     = (const float*)d_in[5];
  const float* v        = (const float*)d_in[6];
  float* out = (float*)d_out;

  // ws layout (fp32): dec[64*1024] | sums[64*32] | part[32*64*1024]  (~8.5 MB)
  float* dec  = (float*)d_ws;
  float* sums = dec + BATCH * H2;
  float* part = sums + BATCH * NCH;

  dec_kernel<<<H2 / 16, 256, 0, stream>>>(s_t_hat, W, bias, dec);
  fused_kernel<<<dim3(NCH, BATCH), 256, 0, stream>>>(
      enc_feat, enc_out, dec, v, mask, part, sums);
  reduce_kernel<<<BATCH, 256, 0, stream>>>(part, sums, out);
}